// Round 5
// baseline (165.988 us; speedup 1.0000x reference)
//
#include <hip/hip_runtime.h>
#include <hip/hip_bf16.h>

typedef __bf16 v4bf __attribute__((ext_vector_type(4)));
typedef __bf16 v8bf __attribute__((ext_vector_type(8)));
typedef float  v4f  __attribute__((ext_vector_type(4)));

namespace {
constexpr int Bb  = 2;
constexpr int Ss  = 2048;
constexpr int Dd  = 640;
constexpr int Hh  = 8;
constexpr int DHh = 80;
constexpr int Mm  = Bb * Ss;          // 4096 rows
// scale * log2(e): softmax done in exp2 domain; folded into Q projection
constexpr float kQScale = 0.11180339887498949f * 1.4426950408889634f;

__device__ __forceinline__ float4 ld4(const float* p) {
  return *reinterpret_cast<const float4*>(p);
}

// async global->LDS, 16B per lane. LDS dest is WAVE-UNIFORM base; HW scatters
// lane i to base + i*16 bytes. Global src is per-lane.
__device__ __forceinline__ void gload16(const __bf16* g, __bf16* l) {
  __builtin_amdgcn_global_load_lds(
      (const __attribute__((address_space(1))) void*)g,
      (__attribute__((address_space(3))) void*)l, 16, 0, 0);
}
}  // namespace

// ---------------------------------------------------------------------------
// Pre-kernel A: x/ehs fp32 -> bf16 (so the QKV GEMM can global_load_lds A).
// ---------------------------------------------------------------------------
__global__ __launch_bounds__(256)
void cast_kernel(const float* __restrict__ x, const float* __restrict__ ehs,
                 __bf16* __restrict__ xb, __bf16* __restrict__ eb) {
  const float* src = (blockIdx.y == 0) ? x : ehs;
  __bf16* dst = (blockIdx.y == 0) ? xb : eb;
  size_t idx = ((size_t)blockIdx.x * 256 + threadIdx.x) * 8;
  float4 f0 = ld4(src + idx), f1 = ld4(src + idx + 4);
  v8bf p;
  p[0]=(__bf16)f0.x; p[1]=(__bf16)f0.y; p[2]=(__bf16)f0.z; p[3]=(__bf16)f0.w;
  p[4]=(__bf16)f1.x; p[5]=(__bf16)f1.y; p[6]=(__bf16)f1.z; p[7]=(__bf16)f1.w;
  *reinterpret_cast<v8bf*>(&dst[idx]) = p;
}

// ---------------------------------------------------------------------------
// Pre-kernel B: W [k][n] fp32 -> Wt [n][k] bf16 (cast + transpose).
// ---------------------------------------------------------------------------
__global__ __launch_bounds__(256)
void wtrans_kernel(const float* __restrict__ Wq, const float* __restrict__ Wk,
                   const float* __restrict__ Wv, const float* __restrict__ Wo,
                   __bf16* __restrict__ Wtq, __bf16* __restrict__ Wtk,
                   __bf16* __restrict__ Wtv, __bf16* __restrict__ Wto) {
  const int z = blockIdx.z;
  const float* W = (z == 0) ? Wq : (z == 1) ? Wk : (z == 2) ? Wv : Wo;
  __bf16* Wt = (z == 0) ? Wtq : (z == 1) ? Wtk : (z == 2) ? Wtv : Wto;
  const int k0 = blockIdx.y * 32, n0 = blockIdx.x * 32;
  __shared__ float t[32][33];
  const int tid = threadIdx.x;
  {
    int kr = tid >> 3, c4 = (tid & 7) * 4;
    float4 f = ld4(W + (size_t)(k0 + kr) * Dd + n0 + c4);
    t[kr][c4 + 0] = f.x; t[kr][c4 + 1] = f.y;
    t[kr][c4 + 2] = f.z; t[kr][c4 + 3] = f.w;
  }
  __syncthreads();
  {
    int nr = tid >> 3, kc = (tid & 7) * 4;
    v4bf p;
#pragma unroll
    for (int u = 0; u < 4; ++u) p[u] = (__bf16)t[kc + u][nr];
    *reinterpret_cast<v4bf*>(&Wt[(size_t)(n0 + nr) * Dd + k0 + kc]) = p;
  }
}

// ---------------------------------------------------------------------------
// m97-style MFMA GEMM core (R5): C = A @ Bt^T, 128x128 tile, BK=32, 4 waves.
// A and B both bf16, staged via global_load_lds width=16 into LINEAR
// [128][32] LDS double buffers (no staging regs, no cvt). One barrier per
// K-step: barrier drains vmcnt (prev stage complete + all waves past prev
// reads), then prefetch next buffer, then ds_read + 16 MFMA on current.
// (T2 LDS swizzle skipped: regime-gated NULL on 2-phase structures.)
// ---------------------------------------------------------------------------
__device__ __forceinline__ void stage_tile(const __bf16* __restrict__ A,
                                           const __bf16* __restrict__ Bt,
                                           __bf16* As, __bf16* Bs, int m0,
                                           int n0, int kb, int w, int srow,
                                           int scol) {
  // wave w stages rows [w*32, w*32+32) of the A-tile and B-tile:
  // 2 instrs each, 16 rows per instr (4 lanes x 16B per 64B row).
  const __bf16* ga = A + (size_t)(m0 + w * 32 + srow) * Dd + kb + scol;
  const __bf16* gb = Bt + (size_t)(n0 + w * 32 + srow) * Dd + kb + scol;
  __bf16* la = As + (w * 32) * 32;  // wave-uniform LDS base
  __bf16* lb = Bs + (w * 32) * 32;
#pragma unroll
  for (int i = 0; i < 2; ++i) {
    gload16(ga + (size_t)i * 16 * Dd, la + i * 16 * 32);
    gload16(gb + (size_t)i * 16 * Dd, lb + i * 16 * 32);
  }
}

__device__ __forceinline__ void gemm_core_lds(const __bf16* __restrict__ A,
                                              const __bf16* __restrict__ Bt,
                                              __bf16* As, __bf16* Bs, int m0,
                                              int n0, int rh, int ch,
                                              v4f acc[4][4]) {
  constexpr int BUF = 128 * 32;  // elements per buffer
  constexpr int NKB = Dd / 32;   // 20 K-steps
  const int tid = threadIdx.x;
  const int w = tid >> 6, lane = tid & 63;
  const int quad = lane >> 4, l15 = lane & 15;
  const int srow = lane >> 2, scol = (lane & 3) * 8;

#pragma unroll
  for (int i = 0; i < 4; ++i)
#pragma unroll
    for (int j = 0; j < 4; ++j) acc[i][j] = (v4f){0.f, 0.f, 0.f, 0.f};

  stage_tile(A, Bt, As, Bs, m0, n0, 0, w, srow, scol);

  for (int it = 0; it < NKB; ++it) {
    __syncthreads();  // drains vmcnt: buf[it&1] ready; prev reads of buf[nxt] done
    if (it + 1 < NKB) {
      const int nb = (it + 1) & 1;
      stage_tile(A, Bt, As + nb * BUF, Bs + nb * BUF, m0, n0, (it + 1) * 32, w,
                 srow, scol);
    }
    const int cur = (it & 1) * BUF;
    v8bf af[4], bv[4];
#pragma unroll
    for (int i = 0; i < 4; ++i)
      af[i] = *reinterpret_cast<const v8bf*>(
          &As[cur + (rh + i * 16 + l15) * 32 + quad * 8]);
#pragma unroll
    for (int j = 0; j < 4; ++j)
      bv[j] = *reinterpret_cast<const v8bf*>(
          &Bs[cur + (ch + j * 16 + l15) * 32 + quad * 8]);
#pragma unroll
    for (int i = 0; i < 4; ++i)
#pragma unroll
      for (int j = 0; j < 4; ++j)
        acc[i][j] = __builtin_amdgcn_mfma_f32_16x16x32_bf16(af[i], bv[j],
                                                            acc[i][j], 0, 0, 0);
  }
}

// QKV projections (A = bf16 xb/eb). z 0/1 -> Q/K row-major (Q scaled in
// epilogue); z==2 -> V stored TRANSPOSED [b][dim][token].
__global__ __launch_bounds__(256)
void gemm_qkv_mfma(const __bf16* __restrict__ xb, const __bf16* __restrict__ eb,
                   const __bf16* __restrict__ Wtq,
                   const __bf16* __restrict__ Wtk,
                   const __bf16* __restrict__ Wtv, __bf16* __restrict__ qb,
                   __bf16* __restrict__ kbuf, __bf16* __restrict__ vb) {
  const int z = blockIdx.z;
  const __bf16* A = (z == 0) ? xb : eb;
  const __bf16* Bt = (z == 0) ? Wtq : (z == 1) ? Wtk : Wtv;
  __bf16* C = (z == 0) ? qb : (z == 1) ? kbuf : vb;
  const float scale = (z == 0) ? kQScale : 1.0f;

  __shared__ __align__(16) __bf16 As[2 * 128 * 32];
  __shared__ __align__(16) __bf16 Bs[2 * 128 * 32];
  const int tid = threadIdx.x;
  const int w = tid >> 6, lane = tid & 63;
  const int quad = lane >> 4, l15 = lane & 15;
  const int m0 = blockIdx.y * 128, n0 = blockIdx.x * 128;
  const int rh = (w >> 1) * 64, ch = (w & 1) * 64;
  v4f acc[4][4];
  gemm_core_lds(A, Bt, As, Bs, m0, n0, rh, ch, acc);

  if (z == 2) {
#pragma unroll
    for (int i = 0; i < 4; ++i)
#pragma unroll
      for (int j = 0; j < 4; ++j) {
        int m = m0 + rh + i * 16 + quad * 4;  // token row
        int n = n0 + ch + j * 16 + l15;       // feature dim
        int bb = m >> 11, tok = m & 2047;
        v4bf pk;
#pragma unroll
        for (int r = 0; r < 4; ++r) pk[r] = (__bf16)acc[i][j][r];
        *reinterpret_cast<v4bf*>(&C[((size_t)bb * Dd + n) * Ss + tok]) = pk;
      }
  } else {
#pragma unroll
    for (int i = 0; i < 4; ++i)
#pragma unroll
      for (int j = 0; j < 4; ++j) {
        int m = m0 + rh + i * 16 + quad * 4;
        int n = n0 + ch + j * 16 + l15;
#pragma unroll
        for (int r = 0; r < 4; ++r)
          C[(size_t)(m + r) * Dd + n] = (__bf16)(acc[i][j][r] * scale);
      }
  }
}

// Out-projection: A = attn-out bf16, out = fp32 + bias.
__global__ __launch_bounds__(256)
void gemm_out_mfma(const __bf16* __restrict__ A, const __bf16* __restrict__ Bt,
                   const float* __restrict__ bias, float* __restrict__ out) {
  __shared__ __align__(16) __bf16 As[2 * 128 * 32];
  __shared__ __align__(16) __bf16 Bs[2 * 128 * 32];
  const int tid = threadIdx.x;
  const int w = tid >> 6, lane = tid & 63;
  const int quad = lane >> 4, l15 = lane & 15;
  const int m0 = blockIdx.y * 128, n0 = blockIdx.x * 128;
  const int rh = (w >> 1) * 64, ch = (w & 1) * 64;
  v4f acc[4][4];
  gemm_core_lds(A, Bt, As, Bs, m0, n0, rh, ch, acc);

#pragma unroll
  for (int i = 0; i < 4; ++i)
#pragma unroll
    for (int j = 0; j < 4; ++j) {
      int m = m0 + rh + i * 16 + quad * 4;
      int n = n0 + ch + j * 16 + l15;
      float bn = bias[n];
#pragma unroll
      for (int r = 0; r < 4; ++r)
        out[(size_t)(m + r) * Dd + n] = acc[i][j][r] + bn;
    }
}

// ---------------------------------------------------------------------------
// Barrier-free key-split MFMA flash attention, software-pipelined (R3/R4;
// UNCHANGED this round — control). Key-split across 4 waves; max-free
// softmax -> partials merge by addition; QK(i)+PV(i-1) fused MFMA stream;
// l-sum via ones-row at dim 80 of V^T; 3-barrier tree-merge epilogue.
// ---------------------------------------------------------------------------
__global__ __launch_bounds__(256, 2)
void attn_mfma_kernel(const __bf16* __restrict__ q,
                      const __bf16* __restrict__ k,
                      const __bf16* __restrict__ vtg, __bf16* __restrict__ o) {
  constexpr int QT = 64;            // q rows per block (all waves)
  constexpr int KT = 32;            // keys per iteration per wave
  constexpr int KW = Ss / 4;        // 512 keys per wave
  constexpr int NIT = KW / KT;      // 16 iterations
  constexpr int LQ = 104;           // K row stride (96 dims + 8 pad)
  constexpr int LV = 40;            // V^T/P row stride (32 keys + 8 pad)
  constexpr int KS = KT * LQ;       // 3328
  constexpr int VS = 96 * LV;       // 3840 (80 data + ones + zeros)
  constexpr int PS = QT * LV;       // 2560
  constexpr int WSZ = KS + VS + PS; // 9728 bf16 per wave
  constexpr int LM = 100;           // merge row stride (f32)

  __shared__ __align__(16) __bf16 smem[4 * WSZ];  // 77824 B

  const int bh = blockIdx.y;
  const int b = bh >> 3, h = bh & 7;
  const int q0 = blockIdx.x * QT;
  const int tid = threadIdx.x;
  const int w = tid >> 6;
  const int lane = tid & 63;
  const int quad = lane >> 4;
  const int l15 = lane & 15;

  __bf16* ksw = smem + w * WSZ;
  __bf16* vtw = ksw + KS;
  __bf16* psw = vtw + VS;

  const __bf16* qg  = q + (size_t)(b * Ss + q0) * Dd + h * DHh;
  const __bf16* kgb = k + (size_t)(b * Ss) * Dd + h * DHh;
  const __bf16* vgb = vtg + ((size_t)b * Dd + h * DHh) * Ss;  // [dim][token]

  // ---- Q fragments straight from global (B-frag: n=q=l15, k=dim) ----
  v8bf qf[4][3];
#pragma unroll
  for (int qt = 0; qt < 4; ++qt)
#pragma unroll
    for (int s = 0; s < 3; ++s) {
      if (s == 2 && quad >= 2) {
        qf[qt][s] = (v8bf){};  // dims 80..95 = pad
      } else {
        qf[qt][s] = *reinterpret_cast<const v8bf*>(
            qg + (size_t)(qt * 16 + l15) * Dd + s * 32 + quad * 8);
      }
    }

  // per-lane staging geometry
  const int kgo = (lane >> 1) * Dd + (lane & 1) * 4;   // global K elem offset
  const int klo = (lane >> 1) * LQ + (lane & 1) * 4;   // LDS K elem offset
  const int vgo = (lane >> 2) * Ss + (lane & 3) * 8;   // global V (b128/lane)
  const int vlo = (lane >> 2) * LV + (lane & 3) * 8;   // LDS V (b128/lane)

  // ---- prologue: pads (written once; loop never touches them) ----
  {
    v8bf z8 = {};
    *reinterpret_cast<v8bf*>(&ksw[(lane >> 1) * LQ + 80 + (lane & 1) * 8]) = z8;
    v8bf pad = {};
    int vr = 80 + (lane >> 2);
    if (vr == 80) {
#pragma unroll
      for (int e = 0; e < 8; ++e) pad[e] = (__bf16)1.f;
    }
    *reinterpret_cast<v8bf*>(&vtw[vr * LV + (lane & 3) * 8]) = pad;
  }
  // ---- stage K(0) ----
  {
    const __bf16* kg = kgb + (size_t)(w * KW) * Dd;
#pragma unroll
    for (int c = 0; c < 10; ++c)
      *reinterpret_cast<v4bf*>(&ksw[klo + c * 8]) =
          *reinterpret_cast<const v4bf*>(kg + kgo + c * 8);
  }

  v4f Oacc[4][6];
#pragma unroll
  for (int qt = 0; qt < 4; ++qt)
#pragma unroll
    for (int mt = 0; mt < 6; ++mt) Oacc[qt][mt] = (v4f){0.f, 0.f, 0.f, 0.f};

  // ---- main loop: per-wave, no barriers; 1-deep software pipeline ----
  for (int it = 0; it < NIT; ++it) {
    const bool pfK = (it + 1 < NIT);
    v4bf kreg[10];
    if (pfK) {
      const __bf16* kg = kgb + (size_t)(w * KW + (it + 1) * KT) * Dd;
#pragma unroll
      for (int c = 0; c < 10; ++c)
        kreg[c] = *reinterpret_cast<const v4bf*>(kg + kgo + c * 8);
    }

    // ---- QK(it): S^T[key][q] ----
    v4f sacc[4][2];
#pragma unroll
    for (int qt = 0; qt < 4; ++qt) {
      sacc[qt][0] = (v4f){0.f, 0.f, 0.f, 0.f};
      sacc[qt][1] = (v4f){0.f, 0.f, 0.f, 0.f};
    }
    __builtin_amdgcn_s_setprio(1);
#pragma unroll
    for (int s = 0; s < 3; ++s) {
      v8bf ak0 = *reinterpret_cast<const v8bf*>(
          &ksw[l15 * LQ + s * 32 + quad * 8]);
      v8bf ak1 = *reinterpret_cast<const v8bf*>(
          &ksw[(16 + l15) * LQ + s * 32 + quad * 8]);
#pragma unroll
      for (int qt = 0; qt < 4; ++qt) {
        sacc[qt][0] = __builtin_amdgcn_mfma_f32_16x16x32_bf16(
            ak0, qf[qt][s], sacc[qt][0], 0, 0, 0);
        sacc[qt][1] = __builtin_amdgcn_mfma_f32_16x16x32_bf16(
            ak1, qf[qt][s], sacc[qt][1], 0, 0, 0);
      }
    }

    // V(it) loads (consumed by PV(it) next iter)
    v8bf vreg[5];
    {
      const __bf16* vg = vgb + (w * KW + it * KT);
#pragma unroll
      for (int c = 0; c < 5; ++c)
        vreg[c] = *reinterpret_cast<const v8bf*>(vg + vgo +
                                                 (size_t)c * 16 * Ss);
    }

    // ---- PV(it-1); exp2(it) fills its shadow ----
    if (it > 0) {
      v8bf bp[4];
#pragma unroll
      for (int qt = 0; qt < 4; ++qt)
        bp[qt] = *reinterpret_cast<const v8bf*>(
            &psw[(qt * 16 + l15) * LV + quad * 8]);
#pragma unroll
      for (int mt = 0; mt < 6; ++mt) {
        v8bf av = *reinterpret_cast<const v8bf*>(
            &vtw[(mt * 16 + l15) * LV + quad * 8]);
#pragma unroll
        for (int qt = 0; qt < 4; ++qt)
          Oacc[qt][mt] = __builtin_amdgcn_mfma_f32_16x16x32_bf16(
              av, bp[qt], Oacc[qt][mt], 0, 0, 0);
      }
    }
    __builtin_amdgcn_s_setprio(0);

    // ---- softmax(it): P = exp2(S) -> ps ----
#pragma unroll
    for (int qt = 0; qt < 4; ++qt)
#pragma unroll
      for (int mt = 0; mt < 2; ++mt) {
        v4bf pk;
#pragma unroll
        for (int r = 0; r < 4; ++r) pk[r] = (__bf16)exp2f(sacc[qt][mt][r]);
        *reinterpret_cast<v4bf*>(
            &psw[(qt * 16 + l15) * LV + mt * 16 + quad * 4]) = pk;
      }

    // ---- commits ----
    if (pfK) {
#pragma unroll
      for (int c = 0; c < 10; ++c)
        *reinterpret_cast<v4bf*>(&ksw[klo + c * 8]) = kreg[c];
    }
#pragma unroll
    for (int c = 0; c < 5; ++c)
      *reinterpret_cast<v8bf*>(&vtw[vlo + c * 16 * LV]) = vreg[c];
  }

  // ---- pipeline epilogue: PV(NIT-1) ----
  {
    v8bf bp[4];
#pragma unroll
    for (int qt = 0; qt < 4; ++qt)
      bp[qt] = *reinterpret_cast<const v8bf*>(
          &psw[(qt * 16 + l15) * LV + quad * 8]);
    __builtin_amdgcn_s_setprio(1);
#pragma unroll
    for (int mt = 0; mt < 6; ++mt) {
      v8bf av = *reinterpret_cast<const v8bf*>(
          &vtw[(mt * 16 + l15) * LV + quad * 8]);
#pragma unroll
      for (int qt = 0; qt < 4; ++qt)
        Oacc[qt][mt] = __builtin_amdgcn_mfma_f32_16x16x32_bf16(
            av, bp[qt], Oacc[qt][mt], 0, 0, 0);
    }
    __builtin_amdgcn_s_setprio(0);
  }

  // ---- tree-merge the 4 per-wave partials ----
  __syncthreads();
  float* mrg = (float*)smem;
  if (w >= 2) {
    float* base = mrg + (w - 2) * (QT * LM);
#pragma unroll
    for (int qt = 0; qt < 4; ++qt)
#pragma unroll
      for (int mt = 0; mt < 6; ++mt)
        *reinterpret_cast<v4f*>(
            &base[(qt * 16 + l15) * LM + mt * 16 + quad * 4]) = Oacc[qt][mt];
  }
  __syncthreads();
  if (w < 2) {
    const float* base = mrg + w * (QT * LM);
#pragma unroll
    for (int qt = 0; qt < 4; ++qt)
#pragma unroll
      for (int mt = 0; mt < 6; ++mt)
        Oacc[qt][mt] += *reinterpret_cast<const v4f*>(
            &base[(qt * 16 + l15) * LM + mt * 16 + quad * 4]);
  }
  __syncthreads();
  if (w == 1) {
#pragma unroll
    for (int qt = 0; qt < 4; ++qt)
#pragma unroll
      for (int mt = 0; mt < 6; ++mt)
        *reinterpret_cast<v4f*>(
            &mrg[(qt * 16 + l15) * LM + mt * 16 + quad * 4]) = Oacc[qt][mt];
  }
  __syncthreads();
  if (w == 0) {
#pragma unroll
    for (int qt = 0; qt < 4; ++qt)
#pragma unroll
      for (int mt = 0; mt < 6; ++mt)
        Oacc[qt][mt] += *reinterpret_cast<const v4f*>(
            &mrg[(qt * 16 + l15) * LM + mt * 16 + quad * 4]);
#pragma unroll
    for (int qt = 0; qt < 4; ++qt) {
      float lsum = __shfl(Oacc[qt][5][0], l15);
      float inv = 1.f / lsum;
      __bf16* og =
          o + (size_t)(b * Ss + q0 + qt * 16 + l15) * Dd + h * DHh;
#pragma unroll
      for (int mt = 0; mt < 5; ++mt) {
        v4bf pk;
#pragma unroll
        for (int r = 0; r < 4; ++r) pk[r] = (__bf16)(Oacc[qt][mt][r] * inv);
        *reinterpret_cast<v4bf*>(&og[mt * 16 + quad * 4]) = pk;
      }
    }
  }
}

extern "C" void kernel_launch(void* const* d_in, const int* in_sizes, int n_in,
                              void* d_out, int out_size, void* d_ws,
                              size_t ws_size, hipStream_t stream) {
  const float* x   = (const float*)d_in[0];
  const float* ehs = (const float*)d_in[1];
  const float* Wq  = (const float*)d_in[2];
  const float* Wk  = (const float*)d_in[3];
  const float* Wv  = (const float*)d_in[4];
  const float* Wo  = (const float*)d_in[5];
  const float* bo  = (const float*)d_in[6];
  float* out = (float*)d_out;

  __bf16* qb  = (__bf16*)d_ws;                 // [4096][640]
  __bf16* kb  = qb + (size_t)Mm * Dd;
  __bf16* vb  = kb + (size_t)Mm * Dd;          // V^T: [2][640][2048]
  __bf16* ab  = vb + (size_t)Mm * Dd;          // attention output
  __bf16* Wtq = ab + (size_t)Mm * Dd;          // [640][640] transposed
  __bf16* Wtk = Wtq + (size_t)Dd * Dd;
  __bf16* Wtv = Wtk + (size_t)Dd * Dd;
  __bf16* Wto = Wtv + (size_t)Dd * Dd;
  __bf16* xb  = Wto + (size_t)Dd * Dd;         // x cast to bf16
  __bf16* eb  = xb + (size_t)Mm * Dd;          // ehs cast to bf16

  cast_kernel<<<dim3(Mm * Dd / (256 * 8), 2), 256, 0, stream>>>(x, ehs, xb, eb);
  wtrans_kernel<<<dim3(Dd / 32, Dd / 32, 4), 256, 0, stream>>>(
      Wq, Wk, Wv, Wo, Wtq, Wtk, Wtv, Wto);
  gemm_qkv_mfma<<<dim3(Dd / 128, Mm / 128, 3), 256, 0, stream>>>(
      xb, eb, Wtq, Wtk, Wtv, qb, kb, vb);
  attn_mfma_kernel<<<dim3(Ss / 64, Bb * Hh), 256, 0, stream>>>(qb, kb, vb, ab);
  gemm_out_mfma<<<dim3(Dd / 128, Mm / 128), 256, 0, stream>>>(ab, Wto, bo,
                                                              out);
}

// Round 7
// 155.778 us; speedup vs baseline: 1.0655x; 1.0655x over previous
//
#include <hip/hip_runtime.h>
#include <hip/hip_bf16.h>

typedef __bf16 v4bf __attribute__((ext_vector_type(4)));
typedef __bf16 v8bf __attribute__((ext_vector_type(8)));
typedef float  v4f  __attribute__((ext_vector_type(4)));

namespace {
constexpr int Bb  = 2;
constexpr int Ss  = 2048;
constexpr int Dd  = 640;
constexpr int Hh  = 8;
constexpr int DHh = 80;
constexpr int Mm  = Bb * Ss;          // 4096 rows
// scale * log2(e): softmax done in exp2 domain; folded into Q projection
constexpr float kQScale = 0.11180339887498949f * 1.4426950408889634f;

__device__ __forceinline__ float4 ld4(const float* p) {
  return *reinterpret_cast<const float4*>(p);
}
}  // namespace

// ---------------------------------------------------------------------------
// Pre-kernel: W [k][n] fp32 -> Wt [n][k] bf16 (cast + transpose).
// ---------------------------------------------------------------------------
__global__ __launch_bounds__(256)
void wtrans_kernel(const float* __restrict__ Wq, const float* __restrict__ Wk,
                   const float* __restrict__ Wv, const float* __restrict__ Wo,
                   __bf16* __restrict__ Wtq, __bf16* __restrict__ Wtk,
                   __bf16* __restrict__ Wtv, __bf16* __restrict__ Wto) {
  const int z = blockIdx.z;
  const float* W = (z == 0) ? Wq : (z == 1) ? Wk : (z == 2) ? Wv : Wo;
  __bf16* Wt = (z == 0) ? Wtq : (z == 1) ? Wtk : (z == 2) ? Wtv : Wto;
  const int k0 = blockIdx.y * 32, n0 = blockIdx.x * 32;
  __shared__ float t[32][33];
  const int tid = threadIdx.x;
  {
    int kr = tid >> 3, c4 = (tid & 7) * 4;
    float4 f = ld4(W + (size_t)(k0 + kr) * Dd + n0 + c4);
    t[kr][c4 + 0] = f.x; t[kr][c4 + 1] = f.y;
    t[kr][c4 + 2] = f.z; t[kr][c4 + 3] = f.w;
  }
  __syncthreads();
  {
    int nr = tid >> 3, kc = (tid & 7) * 4;
    v4bf p;
#pragma unroll
    for (int u = 0; u < 4; ++u) p[u] = (__bf16)t[kc + u][nr];
    *reinterpret_cast<v4bf*>(&Wt[(size_t)(n0 + nr) * Dd + k0 + kc]) = p;
  }
}

// ---------------------------------------------------------------------------
// Double-buffered MFMA GEMM core (R4 reg-staged; R5 LDS variant reverted —
// it was neutral on GEMM speed and its cast pre-kernel cost ~9 us total).
// C = A @ Bt^T. 128x128 tile, BK=32, 4 waves.
// ---------------------------------------------------------------------------
template <bool AF32>
__device__ __forceinline__ void gemm_core_db(const void* __restrict__ Ap,
                                             const __bf16* __restrict__ Bt,
                                             __bf16* As, __bf16* Bs, int m0,
                                             int n0, int rh, int ch,
                                             v4f acc[4][4]) {
  constexpr int BUF = 128 * 40;  // elements per buffer
  constexpr int NKB = Dd / 32;   // 20 K-steps
  const int tid = threadIdx.x;
  const int lane = tid & 63;
  const int quad = lane >> 4, l15 = lane & 15;
  const int lr = tid >> 1;
  const int lk = (tid & 1) * 16;
  const __bf16* Bg = Bt + (size_t)(n0 + lr) * Dd + lk;
  const float* Af = (const float*)Ap;
  const __bf16* Ab = (const __bf16*)Ap;

#pragma unroll
  for (int i = 0; i < 4; ++i)
#pragma unroll
    for (int j = 0; j < 4; ++j) acc[i][j] = (v4f){0.f, 0.f, 0.f, 0.f};

  v8bf a0, a1, b0, b1;
  if constexpr (AF32) {
    const float* ap = Af + (size_t)(m0 + lr) * Dd + lk;
    float4 f0 = ld4(ap), f1 = ld4(ap + 4), f2 = ld4(ap + 8), f3 = ld4(ap + 12);
    a0[0]=(__bf16)f0.x; a0[1]=(__bf16)f0.y; a0[2]=(__bf16)f0.z; a0[3]=(__bf16)f0.w;
    a0[4]=(__bf16)f1.x; a0[5]=(__bf16)f1.y; a0[6]=(__bf16)f1.z; a0[7]=(__bf16)f1.w;
    a1[0]=(__bf16)f2.x; a1[1]=(__bf16)f2.y; a1[2]=(__bf16)f2.z; a1[3]=(__bf16)f2.w;
    a1[4]=(__bf16)f3.x; a1[5]=(__bf16)f3.y; a1[6]=(__bf16)f3.z; a1[7]=(__bf16)f3.w;
  } else {
    const __bf16* ap = Ab + (size_t)(m0 + lr) * Dd + lk;
    a0 = *reinterpret_cast<const v8bf*>(ap);
    a1 = *reinterpret_cast<const v8bf*>(ap + 8);
  }
  b0 = *reinterpret_cast<const v8bf*>(Bg);
  b1 = *reinterpret_cast<const v8bf*>(Bg + 8);
  *reinterpret_cast<v8bf*>(&As[lr * 40 + lk])     = a0;
  *reinterpret_cast<v8bf*>(&As[lr * 40 + lk + 8]) = a1;
  *reinterpret_cast<v8bf*>(&Bs[lr * 40 + lk])     = b0;
  *reinterpret_cast<v8bf*>(&Bs[lr * 40 + lk + 8]) = b1;

  for (int it = 0; it < NKB; ++it) {
    if (it + 1 < NKB) {
      const int kb = (it + 1) * 32;
      if constexpr (AF32) {
        const float* ap = Af + (size_t)(m0 + lr) * Dd + kb + lk;
        float4 f0 = ld4(ap), f1 = ld4(ap + 4), f2 = ld4(ap + 8),
               f3 = ld4(ap + 12);
        a0[0]=(__bf16)f0.x; a0[1]=(__bf16)f0.y; a0[2]=(__bf16)f0.z; a0[3]=(__bf16)f0.w;
        a0[4]=(__bf16)f1.x; a0[5]=(__bf16)f1.y; a0[6]=(__bf16)f1.z; a0[7]=(__bf16)f1.w;
        a1[0]=(__bf16)f2.x; a1[1]=(__bf16)f2.y; a1[2]=(__bf16)f2.z; a1[3]=(__bf16)f2.w;
        a1[4]=(__bf16)f3.x; a1[5]=(__bf16)f3.y; a1[6]=(__bf16)f3.z; a1[7]=(__bf16)f3.w;
      } else {
        const __bf16* ap = Ab + (size_t)(m0 + lr) * Dd + kb + lk;
        a0 = *reinterpret_cast<const v8bf*>(ap);
        a1 = *reinterpret_cast<const v8bf*>(ap + 8);
      }
      b0 = *reinterpret_cast<const v8bf*>(Bg + kb);
      b1 = *reinterpret_cast<const v8bf*>(Bg + kb + 8);
    }
    __syncthreads();
    const int cur = (it & 1) * BUF, nxt = BUF - cur;
    v8bf af[4], bv[4];
#pragma unroll
    for (int i = 0; i < 4; ++i)
      af[i] = *reinterpret_cast<const v8bf*>(
          &As[cur + (rh + i * 16 + l15) * 40 + quad * 8]);
#pragma unroll
    for (int j = 0; j < 4; ++j)
      bv[j] = *reinterpret_cast<const v8bf*>(
          &Bs[cur + (ch + j * 16 + l15) * 40 + quad * 8]);
#pragma unroll
    for (int i = 0; i < 4; ++i)
#pragma unroll
      for (int j = 0; j < 4; ++j)
        acc[i][j] = __builtin_amdgcn_mfma_f32_16x16x32_bf16(af[i], bv[j],
                                                            acc[i][j], 0, 0, 0);
    if (it + 1 < NKB) {
      *reinterpret_cast<v8bf*>(&As[nxt + lr * 40 + lk])     = a0;
      *reinterpret_cast<v8bf*>(&As[nxt + lr * 40 + lk + 8]) = a1;
      *reinterpret_cast<v8bf*>(&Bs[nxt + lr * 40 + lk])     = b0;
      *reinterpret_cast<v8bf*>(&Bs[nxt + lr * 40 + lk + 8]) = b1;
    }
  }
}

// QKV projections. z==0/1 -> Q/K written HEAD-PACKED [b][h][tok][80]
// (Q pre-scaled) so attention's per-head K tiles are CONTIGUOUS (the R6
// theory: [tok][640] head slices made K staging a 32-line gather).
// z==2 -> V stored TRANSPOSED [b][dim][token].
__global__ __launch_bounds__(256)
void gemm_qkv_mfma(const float* __restrict__ x, const float* __restrict__ ehs,
                   const __bf16* __restrict__ Wtq,
                   const __bf16* __restrict__ Wtk,
                   const __bf16* __restrict__ Wtv, __bf16* __restrict__ qb,
                   __bf16* __restrict__ kbuf, __bf16* __restrict__ vb) {
  const int z = blockIdx.z;
  const float* A = (z == 0) ? x : ehs;
  const __bf16* Bt = (z == 0) ? Wtq : (z == 1) ? Wtk : Wtv;
  __bf16* C = (z == 0) ? qb : (z == 1) ? kbuf : vb;
  const float scale = (z == 0) ? kQScale : 1.0f;

  __shared__ __bf16 As[2 * 128 * 40];
  __shared__ __bf16 Bs[2 * 128 * 40];
  const int tid = threadIdx.x;
  const int w = tid >> 6, lane = tid & 63;
  const int quad = lane >> 4, l15 = lane & 15;
  const int m0 = blockIdx.y * 128, n0 = blockIdx.x * 128;
  const int rh = (w >> 1) * 64, ch = (w & 1) * 64;
  v4f acc[4][4];
  gemm_core_db<true>(A, Bt, As, Bs, m0, n0, rh, ch, acc);

  if (z == 2) {
#pragma unroll
    for (int i = 0; i < 4; ++i)
#pragma unroll
      for (int j = 0; j < 4; ++j) {
        int m = m0 + rh + i * 16 + quad * 4;  // token row
        int n = n0 + ch + j * 16 + l15;       // feature dim
        int bb = m >> 11, tok = m & 2047;
        v4bf pk;
#pragma unroll
        for (int r = 0; r < 4; ++r) pk[r] = (__bf16)acc[i][j][r];
        *reinterpret_cast<v4bf*>(&C[((size_t)bb * Dd + n) * Ss + tok]) = pk;
      }
  } else {
    // head-packed epilogue: C[((b*Hh+h)*Ss + tok)*80 + d]
#pragma unroll
    for (int i = 0; i < 4; ++i)
#pragma unroll
      for (int j = 0; j < 4; ++j) {
        int m = m0 + rh + i * 16 + quad * 4;
        int n = n0 + ch + j * 16 + l15;
        int hh = n / DHh, d = n % DHh;
        int bb = m >> 11, tok = m & 2047;
        __bf16* base = &C[(((size_t)bb * Hh + hh) * Ss + tok) * DHh + d];
#pragma unroll
        for (int r = 0; r < 4; ++r)
          base[(size_t)r * DHh] = (__bf16)(acc[i][j][r] * scale);
      }
  }
}

// Out-projection: A = attn-out bf16 [tok][640], out = fp32 + bias.
__global__ __launch_bounds__(256)
void gemm_out_mfma(const __bf16* __restrict__ A, const __bf16* __restrict__ Bt,
                   const float* __restrict__ bias, float* __restrict__ out) {
  __shared__ __bf16 As[2 * 128 * 40];
  __shared__ __bf16 Bs[2 * 128 * 40];
  const int tid = threadIdx.x;
  const int w = tid >> 6, lane = tid & 63;
  const int quad = lane >> 4, l15 = lane & 15;
  const int m0 = blockIdx.y * 128, n0 = blockIdx.x * 128;
  const int rh = (w >> 1) * 64, ch = (w & 1) * 64;
  v4f acc[4][4];
  gemm_core_db<false>(A, Bt, As, Bs, m0, n0, rh, ch, acc);

#pragma unroll
  for (int i = 0; i < 4; ++i)
#pragma unroll
    for (int j = 0; j < 4; ++j) {
      int m = m0 + rh + i * 16 + quad * 4;
      int n = n0 + ch + j * 16 + l15;
      float bn = bias[n];
#pragma unroll
      for (int r = 0; r < 4; ++r)
        out[(size_t)(m + r) * Dd + n] = acc[i][j][r] + bn;
    }
}

// ---------------------------------------------------------------------------
// Barrier-free key-split MFMA flash attention (R4 schedule; R6 address fixes):
// - Q/K now head-packed [b][h][tok][80]: K tile = one contiguous 5120B block
//   -> staged with 5 fully-coalesced b128 loads/lane (was 10 x 32-line
//   gathers -> TA serialization was the modeled 44%-idle stall).
// - grid swapped to (bh, qblock): linear block id % 8 == bh % 8 -> all
//   q-blocks of a head share one XCD L2 (working set 1.3MB << 4MB; was
//   10.5MB thrash, FETCH 2x unique bytes).
// Schedule unchanged: key-split 4 waves, max-free softmax, QK(i)+PV(i-1)
// fused MFMA stream, l-sum ones-row, 3-barrier tree-merge.
// ---------------------------------------------------------------------------
__global__ __launch_bounds__(256, 2)
void attn_mfma_kernel(const __bf16* __restrict__ q,
                      const __bf16* __restrict__ k,
                      const __bf16* __restrict__ vtg, __bf16* __restrict__ o) {
  constexpr int QT = 64;            // q rows per block (all waves)
  constexpr int KT = 32;            // keys per iteration per wave
  constexpr int KW = Ss / 4;        // 512 keys per wave
  constexpr int NIT = KW / KT;      // 16 iterations
  constexpr int LQ = 104;           // K row stride (96 dims + 8 pad)
  constexpr int LV = 40;            // V^T/P row stride (32 keys + 8 pad)
  constexpr int KS = KT * LQ;       // 3328
  constexpr int VS = 96 * LV;       // 3840 (80 data + ones + zeros)
  constexpr int PS = QT * LV;       // 2560
  constexpr int WSZ = KS + VS + PS; // 9728 bf16 per wave
  constexpr int LM = 100;           // merge row stride (f32)

  __shared__ __align__(16) __bf16 smem[4 * WSZ];  // 77824 B

  const int bh = blockIdx.x;        // XCD = linear%8 = bh%8 -> L2 locality
  const int b = bh >> 3, h = bh & 7;
  const int q0 = blockIdx.y * QT;
  const int tid = threadIdx.x;
  const int w = tid >> 6;
  const int lane = tid & 63;
  const int quad = lane >> 4;
  const int l15 = lane & 15;

  __bf16* ksw = smem + w * WSZ;
  __bf16* vtw = ksw + KS;
  __bf16* psw = vtw + VS;

  const __bf16* qg  = q + ((size_t)(b * Hh + h) * Ss + q0) * DHh;
  const __bf16* kgb = k + (size_t)(b * Hh + h) * Ss * DHh;
  const __bf16* vgb = vtg + ((size_t)b * Dd + h * DHh) * Ss;  // [dim][token]

  // ---- Q fragments straight from global (B-frag: n=q=l15, k=dim) ----
  v8bf qf[4][3];
#pragma unroll
  for (int qt = 0; qt < 4; ++qt)
#pragma unroll
    for (int s = 0; s < 3; ++s) {
      if (s == 2 && quad >= 2) {
        qf[qt][s] = (v8bf){};  // dims 80..95 = pad
      } else {
        qf[qt][s] = *reinterpret_cast<const v8bf*>(
            qg + (size_t)(qt * 16 + l15) * DHh + s * 32 + quad * 8);
      }
    }

  // per-lane staging geometry
  // K: tile is contiguous [32][80]; lane handles elems c*512 + lane*8
  int klr[5];
#pragma unroll
  for (int c = 0; c < 5; ++c) {
    int E = c * 512 + lane * 8;
    klr[c] = (E / DHh) * LQ + (E % DHh);   // LDS offset (16B-aligned)
  }
  const int vgo = (lane >> 2) * Ss + (lane & 3) * 8;   // global V (b128/lane)
  const int vlo = (lane >> 2) * LV + (lane & 3) * 8;   // LDS V (b128/lane)

  // ---- prologue: pads (written once; loop never touches them) ----
  {
    v8bf z8 = {};
    *reinterpret_cast<v8bf*>(&ksw[(lane >> 1) * LQ + 80 + (lane & 1) * 8]) = z8;
    v8bf pad = {};
    int vr = 80 + (lane >> 2);
    if (vr == 80) {
#pragma unroll
      for (int e = 0; e < 8; ++e) pad[e] = (__bf16)1.f;
    }
    *reinterpret_cast<v8bf*>(&vtw[vr * LV + (lane & 3) * 8]) = pad;
  }
  // ---- stage K(0): contiguous tile, 5 coalesced b128 per lane ----
  {
    const __bf16* kg = kgb + (size_t)(w * KW) * DHh;
#pragma unroll
    for (int c = 0; c < 5; ++c)
      *reinterpret_cast<v8bf*>(&ksw[klr[c]]) =
          *reinterpret_cast<const v8bf*>(kg + c * 512 + lane * 8);
  }

  v4f Oacc[4][6];
#pragma unroll
  for (int qt = 0; qt < 4; ++qt)
#pragma unroll
    for (int mt = 0; mt < 6; ++mt) Oacc[qt][mt] = (v4f){0.f, 0.f, 0.f, 0.f};

  // ---- main loop: per-wave, no barriers; 1-deep software pipeline ----
  for (int it = 0; it < NIT; ++it) {
    const bool pfK = (it + 1 < NIT);
    v8bf kreg[5];
    if (pfK) {
      const __bf16* kg = kgb + (size_t)(w * KW + (it + 1) * KT) * DHh;
#pragma unroll
      for (int c = 0; c < 5; ++c)
        kreg[c] = *reinterpret_cast<const v8bf*>(kg + c * 512 + lane * 8);
    }

    // ---- QK(it): S^T[key][q] ----
    v4f sacc[4][2];
#pragma unroll
    for (int qt = 0; qt < 4; ++qt) {
      sacc[qt][0] = (v4f){0.f, 0.f, 0.f, 0.f};
      sacc[qt][1] = (v4f){0.f, 0.f, 0.f, 0.f};
    }
    __builtin_amdgcn_s_setprio(1);
#pragma unroll
    for (int s = 0; s < 3; ++s) {
      v8bf ak0 = *reinterpret_cast<const v8bf*>(
          &ksw[l15 * LQ + s * 32 + quad * 8]);
      v8bf ak1 = *reinterpret_cast<const v8bf*>(
          &ksw[(16 + l15) * LQ + s * 32 + quad * 8]);
#pragma unroll
      for (int qt = 0; qt < 4; ++qt) {
        sacc[qt][0] = __builtin_amdgcn_mfma_f32_16x16x32_bf16(
            ak0, qf[qt][s], sacc[qt][0], 0, 0, 0);
        sacc[qt][1] = __builtin_amdgcn_mfma_f32_16x16x32_bf16(
            ak1, qf[qt][s], sacc[qt][1], 0, 0, 0);
      }
    }

    // V(it) loads (consumed by PV(it) next iter)
    v8bf vreg[5];
    {
      const __bf16* vg = vgb + (w * KW + it * KT);
#pragma unroll
      for (int c = 0; c < 5; ++c)
        vreg[c] = *reinterpret_cast<const v8bf*>(vg + vgo +
                                                 (size_t)c * 16 * Ss);
    }

    // ---- PV(it-1); exp2(it) fills its shadow ----
    if (it > 0) {
      v8bf bp[4];
#pragma unroll
      for (int qt = 0; qt < 4; ++qt)
        bp[qt] = *reinterpret_cast<const v8bf*>(
            &psw[(qt * 16 + l15) * LV + quad * 8]);
#pragma unroll
      for (int mt = 0; mt < 6; ++mt) {
        v8bf av = *reinterpret_cast<const v8bf*>(
            &vtw[(mt * 16 + l15) * LV + quad * 8]);
#pragma unroll
        for (int qt = 0; qt < 4; ++qt)
          Oacc[qt][mt] = __builtin_amdgcn_mfma_f32_16x16x32_bf16(
              av, bp[qt], Oacc[qt][mt], 0, 0, 0);
      }
    }
    __builtin_amdgcn_s_setprio(0);

    // ---- softmax(it): P = exp2(S) -> ps ----
#pragma unroll
    for (int qt = 0; qt < 4; ++qt)
#pragma unroll
      for (int mt = 0; mt < 2; ++mt) {
        v4bf pk;
#pragma unroll
        for (int r = 0; r < 4; ++r) pk[r] = (__bf16)exp2f(sacc[qt][mt][r]);
        *reinterpret_cast<v4bf*>(
            &psw[(qt * 16 + l15) * LV + mt * 16 + quad * 4]) = pk;
      }

    // ---- commits ----
    if (pfK) {
#pragma unroll
      for (int c = 0; c < 5; ++c)
        *reinterpret_cast<v8bf*>(&ksw[klr[c]]) = kreg[c];
    }
#pragma unroll
    for (int c = 0; c < 5; ++c)
      *reinterpret_cast<v8bf*>(&vtw[vlo + c * 16 * LV]) = vreg[c];
  }

  // ---- pipeline epilogue: PV(NIT-1) ----
  {
    v8bf bp[4];
#pragma unroll
    for (int qt = 0; qt < 4; ++qt)
      bp[qt] = *reinterpret_cast<const v8bf*>(
          &psw[(qt * 16 + l15) * LV + quad * 8]);
    __builtin_amdgcn_s_setprio(1);
#pragma unroll
    for (int mt = 0; mt < 6; ++mt) {
      v8bf av = *reinterpret_cast<const v8bf*>(
          &vtw[(mt * 16 + l15) * LV + quad * 8]);
#pragma unroll
      for (int qt = 0; qt < 4; ++qt)
        Oacc[qt][mt] = __builtin_amdgcn_mfma_f32_16x16x32_bf16(
            av, bp[qt], Oacc[qt][mt], 0, 0, 0);
    }
    __builtin_amdgcn_s_setprio(0);
  }

  // ---- tree-merge the 4 per-wave partials ----
  __syncthreads();
  float* mrg = (float*)smem;
  if (w >= 2) {
    float* base = mrg + (w - 2) * (QT * LM);
#pragma unroll
    for (int qt = 0; qt < 4; ++qt)
#pragma unroll
      for (int mt = 0; mt < 6; ++mt)
        *reinterpret_cast<v4f*>(
            &base[(qt * 16 + l15) * LM + mt * 16 + quad * 4]) = Oacc[qt][mt];
  }
  __syncthreads();
  if (w < 2) {
    const float* base = mrg + w * (QT * LM);
#pragma unroll
    for (int qt = 0; qt < 4; ++qt)
#pragma unroll
      for (int mt = 0; mt < 6; ++mt)
        Oacc[qt][mt] += *reinterpret_cast<const v4f*>(
            &base[(qt * 16 + l15) * LM + mt * 16 + quad * 4]);
  }
  __syncthreads();
  if (w == 1) {
#pragma unroll
    for (int qt = 0; qt < 4; ++qt)
#pragma unroll
      for (int mt = 0; mt < 6; ++mt)
        *reinterpret_cast<v4f*>(
            &mrg[(qt * 16 + l15) * LM + mt * 16 + quad * 4]) = Oacc[qt][mt];
  }
  __syncthreads();
  if (w == 0) {
#pragma unroll
    for (int qt = 0; qt < 4; ++qt)
#pragma unroll
      for (int mt = 0; mt < 6; ++mt)
        Oacc[qt][mt] += *reinterpret_cast<const v4f*>(
            &mrg[(qt * 16 + l15) * LM + mt * 16 + quad * 4]);
#pragma unroll
    for (int qt = 0; qt < 4; ++qt) {
      float lsum = __shfl(Oacc[qt][5][0], l15);
      float inv = 1.f / lsum;
      __bf16* og =
          o + (size_t)(b * Ss + q0 + qt * 16 + l15) * Dd + h * DHh;
#pragma unroll
      for (int mt = 0; mt < 5; ++mt) {
        v4bf pk;
#pragma unroll
        for (int r = 0; r < 4; ++r) pk[r] = (__bf16)(Oacc[qt][mt][r] * inv);
        *reinterpret_cast<v4bf*>(&og[mt * 16 + quad * 4]) = pk;
      }
    }
  }
}

extern "C" void kernel_launch(void* const* d_in, const int* in_sizes, int n_in,
                              void* d_out, int out_size, void* d_ws,
                              size_t ws_size, hipStream_t stream) {
  const float* x   = (const float*)d_in[0];
  const float* ehs = (const float*)d_in[1];
  const float* Wq  = (const float*)d_in[2];
  const float* Wk  = (const float*)d_in[3];
  const float* Wv  = (const float*)d_in[4];
  const float* Wo  = (const float*)d_in[5];
  const float* bo  = (const float*)d_in[6];
  float* out = (float*)d_out;

  __bf16* qb  = (__bf16*)d_ws;                 // Q head-packed [2][8][2048][80]
  __bf16* kb  = qb + (size_t)Mm * Dd;          // K head-packed [2][8][2048][80]
  __bf16* vb  = kb + (size_t)Mm * Dd;          // V^T: [2][640][2048]
  __bf16* ab  = vb + (size_t)Mm * Dd;          // attention output [tok][640]
  __bf16* Wtq = ab + (size_t)Mm * Dd;          // [640][640] transposed
  __bf16* Wtk = Wtq + (size_t)Dd * Dd;
  __bf16* Wtv = Wtk + (size_t)Dd * Dd;
  __bf16* Wto = Wtv + (size_t)Dd * Dd;

  wtrans_kernel<<<dim3(Dd / 32, Dd / 32, 4), 256, 0, stream>>>(
      Wq, Wk, Wv, Wo, Wtq, Wtk, Wtv, Wto);
  gemm_qkv_mfma<<<dim3(Dd / 128, Mm / 128, 3), 256, 0, stream>>>(
      x, ehs, Wtq, Wtk, Wtv, qb, kb, vb);
  attn_mfma_kernel<<<dim3(Bb * Hh, Ss / 64), 256, 0, stream>>>(qb, kb, vb, ab);
  gemm_out_mfma<<<dim3(Dd / 128, Mm / 128), 256, 0, stream>>>(ab, Wto, bo,
                                                              out);
}